// Round 5
// baseline (207.571 us; speedup 1.0000x reference)
//
#include <hip/hip_runtime.h>

typedef __attribute__((ext_vector_type(8))) short bf16x8;
typedef __attribute__((ext_vector_type(4))) float f32x4;

#define BAR() asm volatile("s_barrier" ::: "memory")
#define WAITV0() asm volatile("s_waitcnt vmcnt(0)" ::: "memory")
#define LGKM0()                                        \
  do {                                                 \
    asm volatile("s_waitcnt lgkmcnt(0)" ::: "memory"); \
    __builtin_amdgcn_sched_barrier(0);                 \
  } while (0)

__device__ __forceinline__ unsigned short f2bf(float f) {
  unsigned int x;
  __builtin_memcpy(&x, &f, 4);
  x += 0x7fffu + ((x >> 16) & 1u);   // RNE round to bf16
  return (unsigned short)(x >> 16);
}

__device__ __forceinline__ float bf2f(unsigned short s) {
  unsigned int x = ((unsigned int)s) << 16;
  float f;
  __builtin_memcpy(&f, &x, 4);
  return f;
}

// async global->LDS, 16B per lane, wave-uniform LDS base
__device__ __forceinline__ void gl_lds16(const unsigned short* gsrc, unsigned short* ldst) {
  __builtin_amdgcn_global_load_lds(
      (const __attribute__((address_space(1))) void*)gsrc,
      (__attribute__((address_space(3))) void*)ldst, 16, 0, 0);
}

// ---------- f32 -> bf16 convert, float4-vectorized ----------
__global__ __launch_bounds__(256) void conv_kernel(const float4* __restrict__ in,
                                                   ushort4* __restrict__ out, int n4) {
  int stride = gridDim.x * blockDim.x;
  for (int i = blockIdx.x * blockDim.x + threadIdx.x; i < n4; i += stride) {
    float4 v = in[i];
    ushort4 o;
    o.x = f2bf(v.x); o.y = f2bf(v.y); o.z = f2bf(v.z); o.w = f2bf(v.w);
    out[i] = o;
  }
}

// ---------- 256x256-tile bf16 NT GEMM, 4-phase/K-tile template schedule ----------
// Per phase: {ds_reads; stage 1 panel of t+1; barrier; lgkmcnt(0); 16 MFMA; barrier}.
// Panels A0/A1/B0/B1 of tile t+1 staged at phases 0..3; vmcnt(0) once at tile end.
// Both-sides XOR swizzle (slot ^= row&7) proven in round 4 (0 bank conflicts).
template <int MODE>
__global__ __launch_bounds__(512, 2) void gemm256(const unsigned short* __restrict__ A,
                                                  const unsigned short* __restrict__ Bm,
                                                  const float* __restrict__ bias0,
                                                  const float* __restrict__ bias1,
                                                  float* __restrict__ out0,
                                                  unsigned short* __restrict__ out1b,
                                                  int nbn) {
  constexpr int K = 1024;
  constexpr int NT = 16;                 // K / 64
  __shared__ __align__(16) unsigned short lds[2][32768];  // [buf][ A:16384 | B:16384 ]

  const int tid = threadIdx.x;
  const int lane = tid & 63, wave = tid >> 6;
  const int wr = wave >> 2, wc = wave & 3;          // 2 x 4 wave grid
  const int l15 = lane & 15, lhi = lane >> 4;

  // bijective XCD swizzle (nwg % 8 == 0 for both grids)
  const int cpx = gridDim.x >> 3;
  const int swz = (blockIdx.x & 7) * cpx + (blockIdx.x >> 3);
  const int m0 = (swz / nbn) * 256, n0 = (swz % nbn) * 256;

  // staging: thread row (tid>>3)&63 within a 64-row chunk; source col pre-swizzled
  const int col16 = (((tid & 7) ^ ((tid >> 3) & 7)) << 3);   // element offset
  const unsigned short* gA = A + (size_t)(m0 + ((tid >> 3) & 63)) * K + col16;
  const unsigned short* gB = Bm + (size_t)(n0 + ((tid >> 3) & 63)) * K + col16;
  const int ldsw = wave * 512;           // wave-uniform ushort offset within 64-row chunk

  // ds_read byte offsets: row*128 + ((kk*64 + lhi*16) ^ ((row&7)<<4))
  const int swzr = (l15 & 7) << 4;
  const int aoff0 = (wr * 128 + l15) * 128 + ((lhi * 16) ^ swzr);
  const int aoff1 = (wr * 128 + l15) * 128 + ((64 + lhi * 16) ^ swzr);
  const int boff0 = (wc * 64 + l15) * 128 + ((lhi * 16) ^ swzr);
  const int boff1 = (wc * 64 + l15) * 128 + ((64 + lhi * 16) ^ swzr);

  f32x4 acc[8][4] = {};

  // panel p of tile t: p 0,1 = A rows [p*128, p*128+128); p 2,3 = B rows likewise
  auto stageP = [&](int t, int p) {
    unsigned short* dst = &lds[t & 1][0];
    if (p < 2) {
#pragma unroll
      for (int s = 0; s < 2; ++s) {
        int c = p * 2 + s;
        gl_lds16(gA + t * 64 + c * 64 * K, dst + c * 4096 + ldsw);
      }
    } else {
#pragma unroll
      for (int s = 0; s < 2; ++s) {
        int c = (p - 2) * 2 + s;
        gl_lds16(gB + t * 64 + c * 64 * K, dst + 16384 + c * 4096 + ldsw);
      }
    }
  };

  // prologue: tile 0 fully staged
  stageP(0, 0); stageP(0, 1); stageP(0, 2); stageP(0, 3);
  WAITV0();
  BAR();

  for (int t = 0; t < NT; ++t) {
    const char* sAb = (const char*)&lds[t & 1][0];
    const char* sBb = sAb + 32768;
    bf16x8 af[4][2], bl[2][2], bh[2][2];

    // ---- phase 0: reads A-low(8) + B-low(4); stage A0(t+1); MFMA Q(0,0) ----
#pragma unroll
    for (int i = 0; i < 4; ++i) {
      af[i][0] = *(const bf16x8*)(sAb + aoff0 + i * 2048);
      af[i][1] = *(const bf16x8*)(sAb + aoff1 + i * 2048);
    }
#pragma unroll
    for (int j = 0; j < 2; ++j) {
      bl[j][0] = *(const bf16x8*)(sBb + boff0 + j * 2048);
      bl[j][1] = *(const bf16x8*)(sBb + boff1 + j * 2048);
    }
    if (t + 1 < NT) stageP(t + 1, 0);
    BAR();
    LGKM0();
    __builtin_amdgcn_s_setprio(1);
#pragma unroll
    for (int i = 0; i < 4; ++i)
#pragma unroll
      for (int j = 0; j < 2; ++j) {
        acc[i][j] = __builtin_amdgcn_mfma_f32_16x16x32_bf16(af[i][0], bl[j][0], acc[i][j], 0, 0, 0);
        acc[i][j] = __builtin_amdgcn_mfma_f32_16x16x32_bf16(af[i][1], bl[j][1], acc[i][j], 0, 0, 0);
      }
    __builtin_amdgcn_s_setprio(0);
    BAR();

    // ---- phase 1: reads B-high(4); stage A1(t+1); MFMA Q(0,1) ----
#pragma unroll
    for (int j = 0; j < 2; ++j) {
      bh[j][0] = *(const bf16x8*)(sBb + boff0 + (j + 2) * 2048);
      bh[j][1] = *(const bf16x8*)(sBb + boff1 + (j + 2) * 2048);
    }
    if (t + 1 < NT) stageP(t + 1, 1);
    BAR();
    LGKM0();
    __builtin_amdgcn_s_setprio(1);
#pragma unroll
    for (int i = 0; i < 4; ++i)
#pragma unroll
      for (int j = 0; j < 2; ++j) {
        acc[i][j + 2] = __builtin_amdgcn_mfma_f32_16x16x32_bf16(af[i][0], bh[j][0], acc[i][j + 2], 0, 0, 0);
        acc[i][j + 2] = __builtin_amdgcn_mfma_f32_16x16x32_bf16(af[i][1], bh[j][1], acc[i][j + 2], 0, 0, 0);
      }
    __builtin_amdgcn_s_setprio(0);
    BAR();

    // ---- phase 2: reads A-high(8); stage B0(t+1); MFMA Q(1,0) ----
#pragma unroll
    for (int i = 0; i < 4; ++i) {
      af[i][0] = *(const bf16x8*)(sAb + aoff0 + (i + 4) * 2048);
      af[i][1] = *(const bf16x8*)(sAb + aoff1 + (i + 4) * 2048);
    }
    if (t + 1 < NT) stageP(t + 1, 2);
    BAR();
    LGKM0();
    __builtin_amdgcn_s_setprio(1);
#pragma unroll
    for (int i = 0; i < 4; ++i)
#pragma unroll
      for (int j = 0; j < 2; ++j) {
        acc[i + 4][j] = __builtin_amdgcn_mfma_f32_16x16x32_bf16(af[i][0], bl[j][0], acc[i + 4][j], 0, 0, 0);
        acc[i + 4][j] = __builtin_amdgcn_mfma_f32_16x16x32_bf16(af[i][1], bl[j][1], acc[i + 4][j], 0, 0, 0);
      }
    __builtin_amdgcn_s_setprio(0);
    BAR();

    // ---- phase 3: stage B1(t+1); MFMA Q(1,1); publish tile t+1 ----
    if (t + 1 < NT) stageP(t + 1, 3);
    BAR();
    __builtin_amdgcn_s_setprio(1);
#pragma unroll
    for (int i = 0; i < 4; ++i)
#pragma unroll
      for (int j = 0; j < 2; ++j) {
        acc[i + 4][j + 2] = __builtin_amdgcn_mfma_f32_16x16x32_bf16(af[i][0], bh[j][0], acc[i + 4][j + 2], 0, 0, 0);
        acc[i + 4][j + 2] = __builtin_amdgcn_mfma_f32_16x16x32_bf16(af[i][1], bh[j][1], acc[i + 4][j + 2], 0, 0, 0);
      }
    __builtin_amdgcn_s_setprio(0);
    if (t + 1 < NT) {
      WAITV0();                          // all 4 panels of tile t+1 landed
      BAR();
    }
  }

  // ---- epilogue ----
  const int gcolb = n0 + wc * 64 + l15;
  const int growb = m0 + wr * 128 + lhi * 4;
  if (MODE == 0) {
    if (n0 < 1024) {
#pragma unroll
      for (int j = 0; j < 4; ++j) {
        const int gcol = gcolb + j * 16;
        const float b0 = bias0[gcol];
#pragma unroll
        for (int i = 0; i < 8; ++i)
#pragma unroll
          for (int r = 0; r < 4; ++r) {
            float z = acc[i][j][r] + b0;
            out0[(size_t)(growb + i * 16 + r) * 1024 + gcol] = 1.0f / (1.0f + __expf(-z));
          }
      }
    } else {
#pragma unroll
      for (int j = 0; j < 4; ++j) {
        const int c = gcolb + j * 16 - 1024;
        const float b1 = bias1[c];
#pragma unroll
        for (int i = 0; i < 8; ++i)
#pragma unroll
          for (int r = 0; r < 4; ++r)
            out1b[(size_t)(growb + i * 16 + r) * 1024 + c] = f2bf(acc[i][j][r] + b1);
      }
    }
  } else {
#pragma unroll
    for (int j = 0; j < 4; ++j) {
      const int gcol = gcolb + j * 16;
      const float dv = bias0[gcol];
#pragma unroll
      for (int i = 0; i < 8; ++i)
#pragma unroll
        for (int r = 0; r < 4; ++r) {
          size_t idx = (size_t)(growb + i * 16 + r) * 1024 + gcol;
          out0[idx] = acc[i][j][r] + dv * bias1[idx];
        }
    }
  }
}

// ---------- chunked scan, pass 1: per-chunk (P = prod a, S = local scan end) ----------
__global__ __launch_bounds__(256) void scan_stats(const float* __restrict__ alpha,
                                                  const unsigned short* __restrict__ Bu,
                                                  float* __restrict__ P,
                                                  float* __restrict__ S) {
  int b = blockIdx.x >> 6;
  int c = (blockIdx.x >> 2) & 15;
  int n = ((blockIdx.x & 3) << 8) | threadIdx.x;
  int bn = (b << 10) | n;
  size_t base = ((size_t)b * 2048 + c * 128) * 1024 + n;
  float h = 0.0f, p = 1.0f;
  for (int t = 0; t < 128; t += 8) {
    float a[8], bb[8];
#pragma unroll
    for (int q = 0; q < 8; ++q) {
      size_t idx = base + (size_t)(t + q) * 1024;
      a[q] = alpha[idx];
      bb[q] = bf2f(Bu[idx]);
    }
#pragma unroll
    for (int q = 0; q < 8; ++q) {
      h = __builtin_fmaf(a[q], h, bb[q]);
      p *= a[q];
    }
  }
  P[c * 8192 + bn] = p;
  S[c * 8192 + bn] = h;
}

// ---------- chunked scan, pass 2: compose carry-in, recompute, emit hs bf16 ----------
__global__ __launch_bounds__(256) void scan_apply(const float* __restrict__ alpha,
                                                  const unsigned short* __restrict__ Bu,
                                                  const float* __restrict__ P,
                                                  const float* __restrict__ S,
                                                  unsigned short* __restrict__ hs) {
  int b = blockIdx.x >> 6;
  int c = (blockIdx.x >> 2) & 15;
  int n = ((blockIdx.x & 3) << 8) | threadIdx.x;
  int bn = (b << 10) | n;
  size_t base = ((size_t)b * 2048 + c * 128) * 1024 + n;
  float h = 0.0f;
  for (int j = 0; j < c; ++j) h = S[j * 8192 + bn] + P[j * 8192 + bn] * h;
  for (int t = 0; t < 128; t += 8) {
    float a[8], bb[8];
#pragma unroll
    for (int q = 0; q < 8; ++q) {
      size_t idx = base + (size_t)(t + q) * 1024;
      a[q] = alpha[idx];
      bb[q] = bf2f(Bu[idx]);
    }
#pragma unroll
    for (int q = 0; q < 8; ++q) {
      h = __builtin_fmaf(a[q], h, bb[q]);
      hs[base + (size_t)(t + q) * 1024] = f2bf(h);
    }
  }
}

extern "C" void kernel_launch(void* const* d_in, const int* in_sizes, int n_in,
                              void* d_out, int out_size, void* d_ws, size_t ws_size,
                              hipStream_t stream) {
  const float* u   = (const float*)d_in[0];
  const float* Waw = (const float*)d_in[1];
  const float* Wab = (const float*)d_in[2];
  const float* WBw = (const float*)d_in[3];
  const float* WBb = (const float*)d_in[4];
  const float* Cw  = (const float*)d_in[5];
  const float* Dv  = (const float*)d_in[6];
  float* y = (float*)d_out;

  const int DM = 1024, NS = 1024;
  const size_t M = 16384;  // B*T

  // Workspace map (verified non-overlapping, round 3):
  //   u_bf  [  0, 32)MB   W_bf [32,36)MB   C_bf [36,38)MB
  //   alpha [ 38,102)MB   Bu_bf[102,134)MB hs   [134,166)MB
  //   Pc    [166,...)     Sc   [167,...)
  char* ws = (char*)d_ws;
  unsigned short* u_bf  = (unsigned short*)(ws);
  unsigned short* W_bf  = (unsigned short*)(ws + (32ull << 20));
  unsigned short* C_bf  = (unsigned short*)(ws + (36ull << 20));
  float*          alpha = (float*)(ws + (38ull << 20));
  unsigned short* Bu_bf = (unsigned short*)(ws + (102ull << 20));
  unsigned short* hs    = (unsigned short*)(ws + (134ull << 20));
  float*          Pc    = (float*)(ws + (166ull << 20));
  float*          Sc    = (float*)(ws + (167ull << 20));

  conv_kernel<<<2048, 256, 0, stream>>>((const float4*)u, (ushort4*)u_bf, (int)(M * DM / 4));
  conv_kernel<<<512, 256, 0, stream>>>((const float4*)Waw, (ushort4*)W_bf, NS * DM / 4);
  conv_kernel<<<512, 256, 0, stream>>>((const float4*)WBw, (ushort4*)(W_bf + (size_t)NS * DM),
                                       NS * DM / 4);
  conv_kernel<<<512, 256, 0, stream>>>((const float4*)Cw, (ushort4*)C_bf, NS * DM / 4);

  // GEMM1: [M,2048] = u @ [W_alpha;W_B]^T  (grid 64x8 = 512 blocks, nbn=8)
  gemm256<0><<<512, 512, 0, stream>>>(u_bf, W_bf, Wab, WBb, alpha, Bu_bf, 8);
  // scan
  scan_stats<<<512, 256, 0, stream>>>(alpha, Bu_bf, Pc, Sc);
  scan_apply<<<512, 256, 0, stream>>>(alpha, Bu_bf, Pc, Sc, hs);
  // GEMM3: y = hs @ C^T + D*u  (grid 64x4 = 256 blocks, nbn=4)
  gemm256<1><<<256, 512, 0, stream>>>(hs, C_bf, Dv, u, y, nullptr, 4);
}

// Round 6
// 203.266 us; speedup vs baseline: 1.0212x; 1.0212x over previous
//
#include <hip/hip_runtime.h>

typedef __attribute__((ext_vector_type(8))) short bf16x8;
typedef __attribute__((ext_vector_type(4))) float f32x4;

#define BAR() asm volatile("s_barrier" ::: "memory")
#define WAITV8() asm volatile("s_waitcnt vmcnt(8)" ::: "memory")
#define WAITV0() asm volatile("s_waitcnt vmcnt(0)" ::: "memory")
#define LGKM0()                                        \
  do {                                                 \
    asm volatile("s_waitcnt lgkmcnt(0)" ::: "memory"); \
    __builtin_amdgcn_sched_barrier(0);                 \
  } while (0)

__device__ __forceinline__ unsigned short f2bf(float f) {
  unsigned int x;
  __builtin_memcpy(&x, &f, 4);
  x += 0x7fffu + ((x >> 16) & 1u);   // RNE round to bf16
  return (unsigned short)(x >> 16);
}

__device__ __forceinline__ float bf2f(unsigned short s) {
  unsigned int x = ((unsigned int)s) << 16;
  float f;
  __builtin_memcpy(&f, &x, 4);
  return f;
}

// async global->LDS, 16B per lane, wave-uniform LDS base
__device__ __forceinline__ void gl_lds16(const unsigned short* gsrc, unsigned short* ldst) {
  __builtin_amdgcn_global_load_lds(
      (const __attribute__((address_space(1))) void*)gsrc,
      (__attribute__((address_space(3))) void*)ldst, 16, 0, 0);
}

// ---------- f32 -> bf16 convert, float4-vectorized ----------
__global__ __launch_bounds__(256) void conv_kernel(const float4* __restrict__ in,
                                                   ushort4* __restrict__ out, int n4) {
  int stride = gridDim.x * blockDim.x;
  for (int i = blockIdx.x * blockDim.x + threadIdx.x; i < n4; i += stride) {
    float4 v = in[i];
    ushort4 o;
    o.x = f2bf(v.x); o.y = f2bf(v.y); o.z = f2bf(v.z); o.w = f2bf(v.w);
    out[i] = o;
  }
}

// ---------- 256x256-tile bf16 NT GEMM, counted-vmcnt 1-tile-deep pipeline ----------
// Per K-tile: { BAR1; stage 8 loads of t+1; vmcnt(8) [t landed, t+1 in flight];
//               BAR2; 4 MFMA phases gated only by per-wave lgkmcnt }.
// Never drains vmcnt to 0 in steady state (T4). Both-sides XOR swizzle (0 conflicts, r4).
template <int MODE>
__global__ __launch_bounds__(512, 2) void gemm256(const unsigned short* __restrict__ A,
                                                  const unsigned short* __restrict__ Bm,
                                                  const float* __restrict__ bias0,
                                                  const float* __restrict__ bias1,
                                                  float* __restrict__ out0,
                                                  unsigned short* __restrict__ out1b,
                                                  int nbn) {
  constexpr int K = 1024;
  constexpr int NT = 16;                 // K / 64
  __shared__ __align__(16) unsigned short lds[2][32768];  // [buf][ A:16384 | B:16384 ]

  const int tid = threadIdx.x;
  const int lane = tid & 63, wave = tid >> 6;
  const int wr = wave >> 2, wc = wave & 3;          // 2 x 4 wave grid
  const int l15 = lane & 15, lhi = lane >> 4;

  // bijective XCD swizzle (nwg % 8 == 0 for both grids)
  const int cpx = gridDim.x >> 3;
  const int swz = (blockIdx.x & 7) * cpx + (blockIdx.x >> 3);
  const int m0 = (swz / nbn) * 256, n0 = (swz % nbn) * 256;

  // staging: thread row (tid>>3)&63 within a 64-row chunk; source col pre-swizzled
  const int col16 = (((tid & 7) ^ ((tid >> 3) & 7)) << 3);   // element offset
  const unsigned short* gA = A + (size_t)(m0 + ((tid >> 3) & 63)) * K + col16;
  const unsigned short* gB = Bm + (size_t)(n0 + ((tid >> 3) & 63)) * K + col16;
  const int ldsw = wave * 512;           // wave-uniform ushort offset within 64-row chunk

  // ds_read byte offsets: row*128 + ((kk*64 + lhi*16) ^ ((row&7)<<4))
  const int swzr = (l15 & 7) << 4;
  const int aoff0 = (wr * 128 + l15) * 128 + ((lhi * 16) ^ swzr);
  const int aoff1 = (wr * 128 + l15) * 128 + ((64 + lhi * 16) ^ swzr);
  const int boff0 = (wc * 64 + l15) * 128 + ((lhi * 16) ^ swzr);
  const int boff1 = (wc * 64 + l15) * 128 + ((64 + lhi * 16) ^ swzr);

  f32x4 acc[8][4] = {};

  // stage all 8 panels (4x A-chunk, 4x B-chunk) of tile t into buf[t&1]
  auto stage = [&](int t) {
    unsigned short* dst = &lds[t & 1][0];
#pragma unroll
    for (int c = 0; c < 4; ++c)
      gl_lds16(gA + t * 64 + c * 64 * K, dst + c * 4096 + ldsw);
#pragma unroll
    for (int c = 0; c < 4; ++c)
      gl_lds16(gB + t * 64 + c * 64 * K, dst + 16384 + c * 4096 + ldsw);
  };

  stage(0);                              // 8 outstanding

  for (int t = 0; t < NT; ++t) {
    const char* sAb = (const char*)&lds[t & 1][0];
    const char* sBb = sAb + 32768;

    BAR();                               // all waves done reading buf[(t+1)&1] (tile t-1)
    if (t + 1 < NT) {
      stage(t + 1);                      // outstanding: 8 -> 16
      WAITV8();                          // tile t's 8 landed; t+1's 8 stay in flight
    } else {
      WAITV0();                          // final tile: nothing staged after it
    }
    BAR();                               // publish tile t to all waves

    bf16x8 af[4][2], bl[2][2], bh[2][2];

    // ---- phase 0: A-low + B-low -> Q(0,0) ----
#pragma unroll
    for (int i = 0; i < 4; ++i) {
      af[i][0] = *(const bf16x8*)(sAb + aoff0 + i * 2048);
      af[i][1] = *(const bf16x8*)(sAb + aoff1 + i * 2048);
    }
#pragma unroll
    for (int j = 0; j < 2; ++j) {
      bl[j][0] = *(const bf16x8*)(sBb + boff0 + j * 2048);
      bl[j][1] = *(const bf16x8*)(sBb + boff1 + j * 2048);
    }
    LGKM0();
    __builtin_amdgcn_s_setprio(1);
#pragma unroll
    for (int i = 0; i < 4; ++i)
#pragma unroll
      for (int j = 0; j < 2; ++j) {
        acc[i][j] = __builtin_amdgcn_mfma_f32_16x16x32_bf16(af[i][0], bl[j][0], acc[i][j], 0, 0, 0);
        acc[i][j] = __builtin_amdgcn_mfma_f32_16x16x32_bf16(af[i][1], bl[j][1], acc[i][j], 0, 0, 0);
      }
    __builtin_amdgcn_s_setprio(0);

    // ---- phase 1: B-high -> Q(0,1) (reuse af) ----
#pragma unroll
    for (int j = 0; j < 2; ++j) {
      bh[j][0] = *(const bf16x8*)(sBb + boff0 + (j + 2) * 2048);
      bh[j][1] = *(const bf16x8*)(sBb + boff1 + (j + 2) * 2048);
    }
    LGKM0();
    __builtin_amdgcn_s_setprio(1);
#pragma unroll
    for (int i = 0; i < 4; ++i)
#pragma unroll
      for (int j = 0; j < 2; ++j) {
        acc[i][j + 2] = __builtin_amdgcn_mfma_f32_16x16x32_bf16(af[i][0], bh[j][0], acc[i][j + 2], 0, 0, 0);
        acc[i][j + 2] = __builtin_amdgcn_mfma_f32_16x16x32_bf16(af[i][1], bh[j][1], acc[i][j + 2], 0, 0, 0);
      }
    __builtin_amdgcn_s_setprio(0);

    // ---- phase 2: A-high -> Q(1,0) (reuse bl) ----
#pragma unroll
    for (int i = 0; i < 4; ++i) {
      af[i][0] = *(const bf16x8*)(sAb + aoff0 + (i + 4) * 2048);
      af[i][1] = *(const bf16x8*)(sAb + aoff1 + (i + 4) * 2048);
    }
    LGKM0();
    __builtin_amdgcn_s_setprio(1);
#pragma unroll
    for (int i = 0; i < 4; ++i)
#pragma unroll
      for (int j = 0; j < 2; ++j) {
        acc[i + 4][j] = __builtin_amdgcn_mfma_f32_16x16x32_bf16(af[i][0], bl[j][0], acc[i + 4][j], 0, 0, 0);
        acc[i + 4][j] = __builtin_amdgcn_mfma_f32_16x16x32_bf16(af[i][1], bl[j][1], acc[i + 4][j], 0, 0, 0);
      }
    __builtin_amdgcn_s_setprio(0);

    // ---- phase 3: Q(1,1) (reuse af + bh, no ds_reads) ----
    __builtin_amdgcn_s_setprio(1);
#pragma unroll
    for (int i = 0; i < 4; ++i)
#pragma unroll
      for (int j = 0; j < 2; ++j) {
        acc[i + 4][j + 2] = __builtin_amdgcn_mfma_f32_16x16x32_bf16(af[i][0], bh[j][0], acc[i + 4][j + 2], 0, 0, 0);
        acc[i + 4][j + 2] = __builtin_amdgcn_mfma_f32_16x16x32_bf16(af[i][1], bh[j][1], acc[i + 4][j + 2], 0, 0, 0);
      }
    __builtin_amdgcn_s_setprio(0);
  }

  // ---- epilogue ----
  const int gcolb = n0 + wc * 64 + l15;
  const int growb = m0 + wr * 128 + lhi * 4;
  if (MODE == 0) {
    if (n0 < 1024) {
#pragma unroll
      for (int j = 0; j < 4; ++j) {
        const int gcol = gcolb + j * 16;
        const float b0 = bias0[gcol];
#pragma unroll
        for (int i = 0; i < 8; ++i)
#pragma unroll
          for (int r = 0; r < 4; ++r) {
            float z = acc[i][j][r] + b0;
            out0[(size_t)(growb + i * 16 + r) * 1024 + gcol] = 1.0f / (1.0f + __expf(-z));
          }
      }
    } else {
#pragma unroll
      for (int j = 0; j < 4; ++j) {
        const int c = gcolb + j * 16 - 1024;
        const float b1 = bias1[c];
#pragma unroll
        for (int i = 0; i < 8; ++i)
#pragma unroll
          for (int r = 0; r < 4; ++r)
            out1b[(size_t)(growb + i * 16 + r) * 1024 + c] = f2bf(acc[i][j][r] + b1);
      }
    }
  } else {
#pragma unroll
    for (int j = 0; j < 4; ++j) {
      const int gcol = gcolb + j * 16;
      const float dv = bias0[gcol];
#pragma unroll
      for (int i = 0; i < 8; ++i)
#pragma unroll
        for (int r = 0; r < 4; ++r) {
          size_t idx = (size_t)(growb + i * 16 + r) * 1024 + gcol;
          out0[idx] = acc[i][j][r] + dv * bias1[idx];
        }
    }
  }
}

// ---------- chunked scan, pass 1: per-chunk (P = prod a, S = local scan end) ----------
__global__ __launch_bounds__(256) void scan_stats(const float* __restrict__ alpha,
                                                  const unsigned short* __restrict__ Bu,
                                                  float* __restrict__ P,
                                                  float* __restrict__ S) {
  int b = blockIdx.x >> 6;
  int c = (blockIdx.x >> 2) & 15;
  int n = ((blockIdx.x & 3) << 8) | threadIdx.x;
  int bn = (b << 10) | n;
  size_t base = ((size_t)b * 2048 + c * 128) * 1024 + n;
  float h = 0.0f, p = 1.0f;
  for (int t = 0; t < 128; t += 8) {
    float a[8], bb[8];
#pragma unroll
    for (int q = 0; q < 8; ++q) {
      size_t idx = base + (size_t)(t + q) * 1024;
      a[q] = alpha[idx];
      bb[q] = bf2f(Bu[idx]);
    }
#pragma unroll
    for (int q = 0; q < 8; ++q) {
      h = __builtin_fmaf(a[q], h, bb[q]);
      p *= a[q];
    }
  }
  P[c * 8192 + bn] = p;
  S[c * 8192 + bn] = h;
}

// ---------- chunked scan, pass 2: compose carry-in, recompute, emit hs bf16 ----------
__global__ __launch_bounds__(256) void scan_apply(const float* __restrict__ alpha,
                                                  const unsigned short* __restrict__ Bu,
                                                  const float* __restrict__ P,
                                                  const float* __restrict__ S,
                                                  unsigned short* __restrict__ hs) {
  int b = blockIdx.x >> 6;
  int c = (blockIdx.x >> 2) & 15;
  int n = ((blockIdx.x & 3) << 8) | threadIdx.x;
  int bn = (b << 10) | n;
  size_t base = ((size_t)b * 2048 + c * 128) * 1024 + n;
  float h = 0.0f;
  for (int j = 0; j < c; ++j) h = S[j * 8192 + bn] + P[j * 8192 + bn] * h;
  for (int t = 0; t < 128; t += 8) {
    float a[8], bb[8];
#pragma unroll
    for (int q = 0; q < 8; ++q) {
      size_t idx = base + (size_t)(t + q) * 1024;
      a[q] = alpha[idx];
      bb[q] = bf2f(Bu[idx]);
    }
#pragma unroll
    for (int q = 0; q < 8; ++q) {
      h = __builtin_fmaf(a[q], h, bb[q]);
      hs[base + (size_t)(t + q) * 1024] = f2bf(h);
    }
  }
}

extern "C" void kernel_launch(void* const* d_in, const int* in_sizes, int n_in,
                              void* d_out, int out_size, void* d_ws, size_t ws_size,
                              hipStream_t stream) {
  const float* u   = (const float*)d_in[0];
  const float* Waw = (const float*)d_in[1];
  const float* Wab = (const float*)d_in[2];
  const float* WBw = (const float*)d_in[3];
  const float* WBb = (const float*)d_in[4];
  const float* Cw  = (const float*)d_in[5];
  const float* Dv  = (const float*)d_in[6];
  float* y = (float*)d_out;

  const int DM = 1024, NS = 1024;
  const size_t M = 16384;  // B*T

  // Workspace map (verified non-overlapping, round 3):
  //   u_bf  [  0, 32)MB   W_bf [32,36)MB   C_bf [36,38)MB
  //   alpha [ 38,102)MB   Bu_bf[102,134)MB hs   [134,166)MB
  //   Pc    [166,...)     Sc   [167,...)
  char* ws = (char*)d_ws;
  unsigned short* u_bf  = (unsigned short*)(ws);
  unsigned short* W_bf  = (unsigned short*)(ws + (32ull << 20));
  unsigned short* C_bf  = (unsigned short*)(ws + (36ull << 20));
  float*          alpha = (float*)(ws + (38ull << 20));
  unsigned short* Bu_bf = (unsigned short*)(ws + (102ull << 20));
  unsigned short* hs    = (unsigned short*)(ws + (134ull << 20));
  float*          Pc    = (float*)(ws + (166ull << 20));
  float*          Sc    = (float*)(ws + (167ull << 20));

  conv_kernel<<<2048, 256, 0, stream>>>((const float4*)u, (ushort4*)u_bf, (int)(M * DM / 4));
  conv_kernel<<<512, 256, 0, stream>>>((const float4*)Waw, (ushort4*)W_bf, NS * DM / 4);
  conv_kernel<<<512, 256, 0, stream>>>((const float4*)WBw, (ushort4*)(W_bf + (size_t)NS * DM),
                                       NS * DM / 4);
  conv_kernel<<<512, 256, 0, stream>>>((const float4*)Cw, (ushort4*)C_bf, NS * DM / 4);

  // GEMM1: [M,2048] = u @ [W_alpha;W_B]^T  (grid 64x8 = 512 blocks, nbn=8)
  gemm256<0><<<512, 512, 0, stream>>>(u_bf, W_bf, Wab, WBb, alpha, Bu_bf, 8);
  // scan
  scan_stats<<<512, 256, 0, stream>>>(alpha, Bu_bf, Pc, Sc);
  scan_apply<<<512, 256, 0, stream>>>(alpha, Bu_bf, Pc, Sc, hs);
  // GEMM3: y = hs @ C^T + D*u  (grid 64x4 = 256 blocks, nbn=4)
  gemm256<1><<<256, 512, 0, stream>>>(hs, C_bf, Dv, u, y, nullptr, 4);
}